// Round 6
// baseline (8025.353 us; speedup 1.0000x reference)
//
#include <hip/hip_runtime.h>
#include <math.h>

// ============================================================================
// PCA + LSTM encoder/decoder on MI355X.
//  - GEMMs: mfma_f32_16x16x32_bf16, 3-term split-bf16 (hi/lo) ~ fp32 accuracy.
//  - Encoder x@K precomputed for all 64 steps in ONE GEMM (zx, bf16 hi/lo).
//  - All 88 recurrent steps in ONE persistent cooperative-launched kernel:
//    weight fragments PINNED in VGPRs (asm keep-alive, 128 regs), c in a
//    register. Steps separated by a CUSTOM 2-level device barrier (thread-0
//    only arrival + s_sleep spin) instead of the slow cg::grid_group::sync.
//  - At step 64 weights transmute in-place to K+R (Kmat read fp32, once).
//  - Workspace: 177 MiB envelope proven in R1-R5 + 4 KiB barrier state.
// ============================================================================

typedef unsigned short US;
typedef __attribute__((ext_vector_type(8))) short bf16x8;
typedef __attribute__((ext_vector_type(4))) float f32x4;

typedef __attribute__((address_space(3))) unsigned int as3_uint;
typedef __attribute__((address_space(1))) unsigned int as1_uint;

#define MFMA(a, b, c) __builtin_amdgcn_mfma_f32_16x16x32_bf16(a, b, c, 0, 0, 0)
#define PIN(x) asm volatile("" : "+v"(x))

__device__ __forceinline__ US f2bf(float x) {   // RNE fp32 -> bf16 bits
  unsigned int u = __float_as_uint(x);
  unsigned int r = 0x7FFFu + ((u >> 16) & 1u);
  return (US)((u + r) >> 16);
}
__device__ __forceinline__ float bf2f(US u) {
  return __uint_as_float(((unsigned int)u) << 16);
}

__device__ __forceinline__ void gl_lds16(const US* g, US* l) {
  __builtin_amdgcn_global_load_lds((const as1_uint*)g, (as3_uint*)l, 16, 0, 0);
}

// ---- elementwise fp32 -> bf16 hi/lo split ----------------------------------
__global__ __launch_bounds__(256) void split_kernel(
    const float* __restrict__ in, US* __restrict__ hi, US* __restrict__ lo, int n4)
{
  int i = blockIdx.x * 256 + threadIdx.x;
  if (i >= n4) return;
  float4 v = reinterpret_cast<const float4*>(in)[i];
  US h0 = f2bf(v.x), h1 = f2bf(v.y), h2 = f2bf(v.z), h3 = f2bf(v.w);
  ushort4 hv = make_ushort4(h0, h1, h2, h3);
  ushort4 lv = make_ushort4(f2bf(v.x - bf2f(h0)), f2bf(v.y - bf2f(h1)),
                            f2bf(v.z - bf2f(h2)), f2bf(v.w - bf2f(h3)));
  reinterpret_cast<ushort4*>(hi)[i] = hv;
  reinterpret_cast<ushort4*>(lo)[i] = lv;
}

// ---- zero initial h frag buffers + barrier state ---------------------------
__global__ void zero_kernel(US* __restrict__ h0, US* __restrict__ l0,
                            unsigned* __restrict__ bar)
{
  int i = blockIdx.x * 256 + threadIdx.x;   // grid covers 65536 exactly
  h0[i] = 0; l0[i] = 0;
  if (i < 1024) bar[i] = 0;
}

// ---- mproj[j] = sum_k mean[k] * comp[j][k] ---------------------------------
__global__ __launch_bounds__(256) void mproj_kernel(
    const float* __restrict__ mean, const float* __restrict__ comp,
    float* __restrict__ mproj)
{
  int j = blockIdx.x;
  const float* row = comp + (size_t)j * 2048;
  float s = 0.f;
  for (int k = threadIdx.x; k < 2048; k += 256) s += mean[k] * row[k];
  __shared__ float ss[4];
  #pragma unroll
  for (int o = 32; o > 0; o >>= 1) s += __shfl_down(s, o, 64);
  if ((threadIdx.x & 63) == 0) ss[threadIdx.x >> 6] = s;
  __syncthreads();
  if (threadIdx.x == 0) mproj[j] = ss[0] + ss[1] + ss[2] + ss[3];
}

// ---- build KT[j'][k] row-major gate-interleaved transpose (for zx GEMM) ----
// j' = 4*u + g  <->  source col g*2048+u.
__global__ __launch_bounds__(256) void build_kt(
    const float* __restrict__ src, US* __restrict__ t_hi, US* __restrict__ t_lo)
{
  __shared__ float tile[64][65];
  const int jblk = blockIdx.x >> 5;
  const int kblk = blockIdx.x & 31;
  const int j0 = jblk * 64;
  const int u0 = j0 >> 2;
  const int k0 = kblk * 64;
  const int tid = threadIdx.x;
  const int cc = tid & 63;
  const int g = cc >> 4, uo = cc & 15;
  const int col = g * 2048 + u0 + uo;
  const int kl0 = tid >> 6;
  #pragma unroll
  for (int r = 0; r < 16; ++r) {
    int kl = r * 4 + kl0;
    tile[4 * uo + g][kl] = src[(size_t)(k0 + kl) * 8192 + col];
  }
  __syncthreads();
  const int kl = tid & 63;
  const int jl0 = tid >> 6;
  #pragma unroll
  for (int r = 0; r < 16; ++r) {
    int jl = r * 4 + jl0;
    float v = tile[jl][kl];
    US hv = f2bf(v);
    size_t o = (size_t)(j0 + jl) * 2048 + (size_t)(k0 + kl);
    t_hi[o] = hv;
    t_lo[o] = f2bf(v - bf2f(hv));
  }
}

// ---- build fragment-linear split weights W'[j'][k] -------------------------
// lin = ((jg*64+kc)*64+l)*8+e ; jg=j'>>4; kc=k>>5; l=((k>>3)&3)*16+(j'&15); e=k&7
__global__ __launch_bounds__(256) void build_wfrag(
    const float* __restrict__ src, US* __restrict__ t_hi, US* __restrict__ t_lo)
{
  __shared__ float tile[64][68];          // [j'local][k_local]
  const int ub = blockIdx.x >> 5;
  const int kb = blockIdx.x & 31;
  const int u0 = ub * 16, k0 = kb * 64;
  const int jg0 = ub * 4, kc0 = kb * 2;
  const int tid = threadIdx.x;

  const int g = tid >> 6, r2 = (tid >> 2) & 15, c4 = tid & 3;
  #pragma unroll
  for (int rr = 0; rr < 4; ++rr) {
    int row = rr * 16 + r2;
    size_t off = (size_t)(k0 + row) * 8192 + g * 2048 + u0 + c4 * 4;
    float4 v = *reinterpret_cast<const float4*>(src + off);
    tile[4 * (c4 * 4 + 0) + g][row] = v.x;
    tile[4 * (c4 * 4 + 1) + g][row] = v.y;
    tile[4 * (c4 * 4 + 2) + g][row] = v.z;
    tile[4 * (c4 * 4 + 3) + g][row] = v.w;
  }
  __syncthreads();

  #pragma unroll
  for (int it = 0; it < 2; ++it) {
    int idx = it * 256 + tid;
    int l = idx & 63, kcl = (idx >> 6) & 1, jgl = idx >> 7;
    int jloc = jgl * 16 + (l & 15);
    int kl = kcl * 32 + (l >> 4) * 8;
    float4 v0 = *reinterpret_cast<const float4*>(&tile[jloc][kl]);
    float4 v1 = *reinterpret_cast<const float4*>(&tile[jloc][kl + 4]);
    float f[8] = {v0.x, v0.y, v0.z, v0.w, v1.x, v1.y, v1.z, v1.w};
    unsigned int hp[4], lp[4];
    #pragma unroll
    for (int q = 0; q < 4; ++q) {
      US h0 = f2bf(f[2 * q]),     h1 = f2bf(f[2 * q + 1]);
      US s0 = f2bf(f[2 * q] - bf2f(h0));
      US s1 = f2bf(f[2 * q + 1] - bf2f(h1));
      hp[q] = (unsigned int)h0 | ((unsigned int)h1 << 16);
      lp[q] = (unsigned int)s0 | ((unsigned int)s1 << 16);
    }
    size_t base = (((size_t)(jg0 + jgl) * 64 + (kc0 + kcl)) * 64 + l) * 8;
    *reinterpret_cast<uint4*>(t_hi + base) = make_uint4(hp[0], hp[1], hp[2], hp[3]);
    *reinterpret_cast<uint4*>(t_lo + base) = make_uint4(lp[0], lp[1], lp[2], lp[3]);
  }
}

// ---- 128-row tiled GEMM, LDS-staged via global_load_lds, XOR swizzle -------
// C[m][n] = sum_k A[m][k]*B[n][k], K = 2048, 3-term split. XCD block swizzle.
// EPI 0: pca (sub mproj, row remap b*64+t -> t*32+b, bf16 split store)
// EPI 2: bf16 hi/lo split store at [m][ldo].
template<int NT, int EPI>
__global__ __launch_bounds__(256, 2) void gemm128(
    const US* __restrict__ Ah, const US* __restrict__ Al,
    const US* __restrict__ Bh, const US* __restrict__ Bl,
    const float* __restrict__ mproj,
    US* __restrict__ out0, US* __restrict__ out1,
    int MB, int ldo)
{
  constexpr int BN = NT * 32;
  __shared__ US sAh[128 * 64], sAl[128 * 64];
  __shared__ US sBh[BN * 64],  sBl[BN * 64];
  const int tid = threadIdx.x;
  const int w = tid >> 6, l = tid & 63;
  const int l16 = l & 15, lq = l >> 4;
  const int cpx = gridDim.x >> 3;
  const int swz = (blockIdx.x & 7) * cpx + (blockIdx.x >> 3);
  const int bm = swz % MB, bn = swz / MB;
  const int wm = w & 1, wn = w >> 1;
  const int AR0 = bm * 128, BR0 = bn * BN;

  f32x4 acc[4][NT];
  #pragma unroll
  for (int i = 0; i < 4; ++i)
    #pragma unroll
    for (int j = 0; j < NT; ++j) acc[i][j] = {0.f, 0.f, 0.f, 0.f};

  for (int k0 = 0; k0 < 2048; k0 += 64) {
    {
      #pragma unroll
      for (int i = 0; i < 4; ++i) {
        int c = (w * 4 + i) * 64 + l;
        int row = c >> 3, kc = c & 7;
        size_t go = (size_t)(AR0 + row) * 2048 + (k0 + ((kc ^ (row & 7)) << 3));
        gl_lds16(Ah + go, sAh + (w * 4 + i) * 512);
        gl_lds16(Al + go, sAl + (w * 4 + i) * 512);
      }
      constexpr int IPW = BN >> 5;
      #pragma unroll
      for (int i = 0; i < IPW; ++i) {
        int c = (w * IPW + i) * 64 + l;
        int row = c >> 3, kc = c & 7;
        size_t go = (size_t)(BR0 + row) * 2048 + (k0 + ((kc ^ (row & 7)) << 3));
        gl_lds16(Bh + go, sBh + (w * IPW + i) * 512);
        gl_lds16(Bl + go, sBl + (w * IPW + i) * 512);
      }
    }
    __syncthreads();
    #pragma unroll
    for (int ks = 0; ks < 2; ++ks) {
      const int kb = ks * 64 + lq * 16;
      bf16x8 ah[4], al[4], bh[NT], bl[NT];
      #pragma unroll
      for (int mt = 0; mt < 4; ++mt) {
        int r = wm * 64 + mt * 16 + l16;
        int off = r * 64 + ((kb ^ ((r & 7) << 4)) >> 1);
        ah[mt] = *reinterpret_cast<const bf16x8*>(sAh + off);
        al[mt] = *reinterpret_cast<const bf16x8*>(sAl + off);
      }
      #pragma unroll
      for (int nt = 0; nt < NT; ++nt) {
        int r = wn * (BN / 2) + nt * 16 + l16;
        int off = r * 64 + ((kb ^ ((r & 7) << 4)) >> 1);
        bh[nt] = *reinterpret_cast<const bf16x8*>(sBh + off);
        bl[nt] = *reinterpret_cast<const bf16x8*>(sBl + off);
      }
      #pragma unroll
      for (int mt = 0; mt < 4; ++mt)
        #pragma unroll
        for (int nt = 0; nt < NT; ++nt) {
          acc[mt][nt] = MFMA(ah[mt], bh[nt], acc[mt][nt]);
          acc[mt][nt] = MFMA(al[mt], bh[nt], acc[mt][nt]);
          acc[mt][nt] = MFMA(ah[mt], bl[nt], acc[mt][nt]);
        }
    }
    __syncthreads();
  }

  #pragma unroll
  for (int mt = 0; mt < 4; ++mt)
    #pragma unroll
    for (int nt = 0; nt < NT; ++nt) {
      int j = BR0 + wn * (BN / 2) + nt * 16 + l16;
      float mp = (EPI == 0) ? mproj[j] : 0.f;
      #pragma unroll
      for (int r = 0; r < 4; ++r) {
        int m = AR0 + wm * 64 + mt * 16 + lq * 4 + r;
        float v = acc[mt][nt][r] - mp;
        if constexpr (EPI == 0) {
          int t = m & 63, b = m >> 6;
          size_t o = (size_t)(t * 32 + b) * ldo + j;
          US hv = f2bf(v);
          out0[o] = hv;
          out1[o] = f2bf(v - bf2f(hv));
        } else {
          size_t o = (size_t)m * ldo + j;
          US hv = f2bf(v);
          out0[o] = hv;
          out1[o] = f2bf(v - bf2f(hv));
        }
      }
    }
}

// ---- fast 2-level device barrier (thread-0 arrival, s_sleep spin) ----------
// bar: 32 group counters at bar[g*16] (64B apart), root at bar[512],
// generation at bar[520]. Cumulative counts -> no reset, deterministic.
__device__ __forceinline__ void gbar(int s, unsigned* bar)
{
  __threadfence();                      // release this block's writes
  __syncthreads();
  if (threadIdx.x == 0) {
    const int g = blockIdx.x >> 3;      // 32 groups of 8 blocks
    unsigned a = __hip_atomic_fetch_add(&bar[g * 16], 1u,
                    __ATOMIC_ACQ_REL, __HIP_MEMORY_SCOPE_AGENT);
    if (a == (unsigned)(8 * (s + 1) - 1)) {
      unsigned r = __hip_atomic_fetch_add(&bar[512], 1u,
                      __ATOMIC_ACQ_REL, __HIP_MEMORY_SCOPE_AGENT);
      if (r == (unsigned)(32 * (s + 1) - 1))
        __hip_atomic_store(&bar[520], (unsigned)(s + 1),
                           __ATOMIC_RELEASE, __HIP_MEMORY_SCOPE_AGENT);
    }
    while (__hip_atomic_load(&bar[520], __ATOMIC_ACQUIRE,
                             __HIP_MEMORY_SCOPE_AGENT) < (unsigned)(s + 1)) {
      __builtin_amdgcn_s_sleep(2);
    }
  }
  __syncthreads();
  __threadfence();                      // acquire side for all threads
}

// ---- persistent LSTM: all 88 steps, weights PINNED in VGPRs ----------------
// 256 blocks (block b owns units [8b,8b+8) = j' [32b,32b+32)), 512 thr = 8
// waves; wave kq holds W frags for jg in {2b,2b+1}, kc in [8kq,8kq+8).
// At s==64: W := resplit(R + K), K read fp32 straight from Kmat (once).
__global__ __launch_bounds__(512, 2) void lstm_persist(
    const US* __restrict__ rtf_hi, const US* __restrict__ rtf_lo,
    const float* __restrict__ Kmat,
    const US* __restrict__ zx_hi, const US* __restrict__ zx_lo,
    const float* __restrict__ bias,
    US* __restrict__ h_hi0, US* __restrict__ h_lo0,
    US* __restrict__ h_hi1, US* __restrict__ h_lo1,
    unsigned* __restrict__ bar,
    float* __restrict__ out)
{
  __shared__ float red[8][32][33];
  const int tid = threadIdx.x;
  const int kq = tid >> 6, l = tid & 63;
  const int b = blockIdx.x;
  const int l16 = l & 15, lq = l >> 4;

  // ---- load weight fragments (R) into registers and PIN them ----
  bf16x8 Wh[2][8], Wl[2][8];
  #pragma unroll
  for (int jgl = 0; jgl < 2; ++jgl)
    #pragma unroll
    for (int kcl = 0; kcl < 8; ++kcl) {
      size_t o = (((size_t)(b * 2 + jgl) * 64 + kq * 8 + kcl) * 64 + l) * 8;
      Wh[jgl][kcl] = *reinterpret_cast<const bf16x8*>(rtf_hi + o);
      Wl[jgl][kcl] = *reinterpret_cast<const bf16x8*>(rtf_lo + o);
      PIN(Wh[jgl][kcl]);
      PIN(Wl[jgl][kcl]);
    }

  // ---- cell-role constants (tid < 256: one (batch m, unit uu)) ----
  const int m = tid >> 3, uu = tid & 7;
  const int u = b * 8 + uu;
  float bz0 = 0.f, bz1 = 0.f, bz2 = 0.f, bz3 = 0.f, creg = 0.f;
  if (tid < 256) {
    bz0 = bias[u]; bz1 = bias[u + 2048];
    bz2 = bias[u + 4096]; bz3 = bias[u + 6144];
  }
  const int kcw = u >> 5, mhw = m >> 4;
  const int lw = ((u >> 3) & 3) * 16 + (m & 15);
  const size_t hwidx = (((size_t)kcw * 2 + mhw) * 64 + lw) * 8 + (u & 7);

  for (int s = 0; s < 88; ++s) {
    const int par = s & 1;
    const US* hfh = par ? h_hi1 : h_hi0;
    const US* hfl = par ? h_lo1 : h_lo0;
    US* hoh = par ? h_hi0 : h_hi1;
    US* hol = par ? h_lo0 : h_lo1;

    if (s == 64) {
      // transmute W := resplit(R + K); K read fp32 straight from input
      #pragma unroll
      for (int jgl = 0; jgl < 2; ++jgl) {
        const int jp = (b * 2 + jgl) * 16 + l16;       // j' = 4u+g
        const int col = (jp & 3) * 2048 + (jp >> 2);   // source col g*2048+u
        #pragma unroll
        for (int kcl = 0; kcl < 8; ++kcl) {
          const int k0 = (kq * 8 + kcl) * 32 + lq * 8;
          #pragma unroll
          for (int e = 0; e < 8; ++e) {
            float kv = Kmat[(size_t)(k0 + e) * 8192 + col];
            float wv = bf2f((US)Wh[jgl][kcl][e]) + bf2f((US)Wl[jgl][kcl][e]) + kv;
            US hv = f2bf(wv);
            Wh[jgl][kcl][e] = (short)hv;
            Wl[jgl][kcl][e] = (short)f2bf(wv - bf2f(hv));
          }
          PIN(Wh[jgl][kcl]);
          PIN(Wl[jgl][kcl]);
        }
      }
    }

    // ---- partial z: wave kq covers k in [kq*256, kq*256+256) ----
    f32x4 acc00 = {0.f,0.f,0.f,0.f}, acc01 = {0.f,0.f,0.f,0.f};
    f32x4 acc10 = {0.f,0.f,0.f,0.f}, acc11 = {0.f,0.f,0.f,0.f};
    #pragma unroll
    for (int kcl = 0; kcl < 8; ++kcl) {
      const int kc = kq * 8 + kcl;
      const US* ah = hfh + ((size_t)kc * 2 * 64 + l) * 8;
      const US* al = hfl + ((size_t)kc * 2 * 64 + l) * 8;
      bf16x8 a0h = *reinterpret_cast<const bf16x8*>(ah);
      bf16x8 a1h = *reinterpret_cast<const bf16x8*>(ah + 512);
      bf16x8 a0l = *reinterpret_cast<const bf16x8*>(al);
      bf16x8 a1l = *reinterpret_cast<const bf16x8*>(al + 512);
      acc00 = MFMA(a0h, Wh[0][kcl], acc00);
      acc01 = MFMA(a0h, Wh[1][kcl], acc01);
      acc10 = MFMA(a1h, Wh[0][kcl], acc10);
      acc11 = MFMA(a1h, Wh[1][kcl], acc11);
      acc00 = MFMA(a0l, Wh[0][kcl], acc00);
      acc01 = MFMA(a0l, Wh[1][kcl], acc01);
      acc10 = MFMA(a1l, Wh[0][kcl], acc10);
      acc11 = MFMA(a1l, Wh[1][kcl], acc11);
      acc00 = MFMA(a0h, Wl[0][kcl], acc00);
      acc01 = MFMA(a0h, Wl[1][kcl], acc01);
      acc10 = MFMA(a1h, Wl[0][kcl], acc10);
      acc11 = MFMA(a1h, Wl[1][kcl], acc11);
    }

    // ---- write partials, reduce 8-way, cell update ----
    #pragma unroll
    for (int r = 0; r < 4; ++r) {
      red[kq][l16][0 * 16 + lq * 4 + r]       = acc00[r];
      red[kq][16 + l16][0 * 16 + lq * 4 + r]  = acc01[r];
      red[kq][l16][1 * 16 + lq * 4 + r]       = acc10[r];
      red[kq][16 + l16][1 * 16 + lq * 4 + r]  = acc11[r];
    }
    __syncthreads();
    if (tid < 256) {
      float z0 = bz0, z1 = bz1, z2 = bz2, z3 = bz3;
      #pragma unroll
      for (int q = 0; q < 8; ++q) {
        z0 += red[q][uu * 4 + 0][m];
        z1 += red[q][uu * 4 + 1][m];
        z2 += red[q][uu * 4 + 2][m];
        z3 += red[q][uu * 4 + 3][m];
      }
      if (s < 64) {
        size_t zo = (size_t)(s * 32 + m) * 8192 + (size_t)u * 4;
        z0 += bf2f(zx_hi[zo + 0]) + bf2f(zx_lo[zo + 0]);
        z1 += bf2f(zx_hi[zo + 1]) + bf2f(zx_lo[zo + 1]);
        z2 += bf2f(zx_hi[zo + 2]) + bf2f(zx_lo[zo + 2]);
        z3 += bf2f(zx_hi[zo + 3]) + bf2f(zx_lo[zo + 3]);
      }
      float gi = 1.f / (1.f + expf(-z0));
      float gf = 1.f / (1.f + expf(-z1));
      float gg = tanhf(z2);
      float go = 1.f / (1.f + expf(-z3));
      creg = gf * creg + gi * gg;
      float hn = go * tanhf(creg);
      US hv = f2bf(hn);
      hoh[hwidx] = hv;
      hol[hwidx] = f2bf(hn - bf2f(hv));
      if (s >= 64) out[((size_t)m * 24 + (s - 64)) * 2048 + u] = hn;
    }
    gbar(s, bar);
  }
}

// ============================================================================
extern "C" void kernel_launch(void* const* d_in, const int* in_sizes, int n_in,
                              void* d_out, int out_size, void* d_ws, size_t ws_size,
                              hipStream_t stream)
{
  const float* inputs = (const float*)d_in[0];   // (32,64,2048,1)
  const float* comp   = (const float*)d_in[1];   // (2048,2048)
  const float* mean   = (const float*)d_in[2];   // (2048,)
  const float* Kmat   = (const float*)d_in[3];   // (2048,8192)
  const float* Rmat   = (const float*)d_in[4];   // (2048,8192)
  const float* bias   = (const float*)d_in[5];   // (8192,)
  float* out = (float*)d_out;                    // (32,24,2048)

  // ---- workspace layout (177 MiB envelope, proven in R1-R5) ----
  const size_t MiB = 1024 * 1024;
  char* base = (char*)d_ws;
  US* zx_hi   = (US*)(base);                     // [0,32)   2048x8192 bf16
  US* zx_lo   = (US*)(base + 32 * MiB);          // [32,64)
  US* KT_hi   = (US*)(base + 64 * MiB);          // [64,96)  row-major K^T
  US* KT_lo   = (US*)(base + 96 * MiB);          // [96,128)
  US* RTf_hi  = KT_hi;                           // over dead KT (after zx gemm)
  US* RTf_lo  = KT_lo;
  US* flat_hi = (US*)(base + 128 * MiB);         // [128,136)
  US* flat_lo = (US*)(base + 136 * MiB);         // [136,144)
  US* comp_hi = (US*)(base + 144 * MiB);         // [144,152)
  US* comp_lo = (US*)(base + 152 * MiB);         // [152,160)
  US* xs_hi   = (US*)(base + 160 * MiB);         // [160,168)
  US* xs_lo   = (US*)(base + 168 * MiB);         // [168,176)
  char* Mz = base + 176 * MiB;
  float* mproj = (float*)(Mz);
  US* hh0 = (US*)(Mz + 64 * 1024);
  US* hl0 = (US*)(Mz + 256 * 1024);
  US* hh1 = (US*)(Mz + 448 * 1024);
  US* hl1 = (US*)(Mz + 640 * 1024);
  unsigned* bar = (unsigned*)(Mz + 832 * 1024);  // 4 KiB barrier state

  // ---- prep ----
  split_kernel<<<4096, 256, 0, stream>>>(inputs, flat_hi, flat_lo, 1048576);
  split_kernel<<<4096, 256, 0, stream>>>(comp,   comp_hi, comp_lo, 1048576);
  mproj_kernel<<<2048, 256, 0, stream>>>(mean, comp, mproj);
  build_kt<<<4096, 256, 0, stream>>>(Kmat, KT_hi, KT_lo);
  zero_kernel<<<256, 256, 0, stream>>>(hh0, hl0, bar);

  // xs = (flat - mean) @ comp^T  (2048 x 2048), rows remapped to t*32+b
  gemm128<2, 0><<<512, 256, 0, stream>>>(flat_hi, flat_lo, comp_hi, comp_lo,
                                         mproj, xs_hi, xs_lo, 16, 2048);
  // zx = xs @ K^T  (2048 x 8192, gate-interleaved cols), bf16 hi/lo store
  gemm128<4, 2><<<1024, 256, 0, stream>>>(xs_hi, xs_lo, KT_hi, KT_lo,
                                          nullptr, zx_hi, zx_lo, 16, 8192);
  // RTf (fragment-linear R^T) over the now-dead KT region
  build_wfrag<<<4096, 256, 0, stream>>>(Rmat, RTf_hi, RTf_lo);

  // ---- all 88 steps in one persistent kernel (cooperative launch for
  //      guaranteed co-residency; custom barrier used inside) ----
  const US* a_rtf_hi = RTf_hi; const US* a_rtf_lo = RTf_lo;
  const float* a_kmat = Kmat;
  const US* a_zx_hi = zx_hi;   const US* a_zx_lo = zx_lo;
  const float* a_bias = bias;
  US* a_hh0 = hh0; US* a_hl0 = hl0; US* a_hh1 = hh1; US* a_hl1 = hl1;
  unsigned* a_bar = bar;
  float* a_out = out;
  void* args[] = {
    (void*)&a_rtf_hi, (void*)&a_rtf_lo, (void*)&a_kmat,
    (void*)&a_zx_hi, (void*)&a_zx_lo, (void*)&a_bias,
    (void*)&a_hh0, (void*)&a_hl0, (void*)&a_hh1, (void*)&a_hl1,
    (void*)&a_bar, (void*)&a_out
  };
  hipLaunchCooperativeKernel((void*)lstm_persist, dim3(256), dim3(512),
                             args, 0, stream);
}

// Round 7
// 1859.701 us; speedup vs baseline: 4.3154x; 4.3154x over previous
//
#include <hip/hip_runtime.h>
#include <math.h>

// ============================================================================
// PCA + LSTM encoder/decoder on MI355X.
//  - GEMMs: mfma_f32_16x16x32_bf16, 3-term split-bf16 (hi/lo) ~ fp32 accuracy.
//  - Encoder x@K precomputed for all 64 steps in ONE GEMM (zx, bf16 hi/lo).
//  - All 88 recurrent steps in ONE persistent cooperative-launched kernel.
//    * Weights in VGPRs: amdgpu_waves_per_eu(2,2) => 256-reg budget (the R6
//      failure was the compiler capping at 128 regs and spilling).
//    * Custom barrier: RELAXED spin + ONE acquire fence at exit (the R5/R6
//      failure was an L2-invalidate per poll iteration).
//  - At step 64 weights transmute in-place to K+R (Kmat read fp32, once).
//  - Workspace: 177 MiB envelope proven in R1-R5 + 4 KiB barrier state.
// ============================================================================

typedef unsigned short US;
typedef __attribute__((ext_vector_type(8))) short bf16x8;
typedef __attribute__((ext_vector_type(4))) float f32x4;

typedef __attribute__((address_space(3))) unsigned int as3_uint;
typedef __attribute__((address_space(1))) unsigned int as1_uint;

#define MFMA(a, b, c) __builtin_amdgcn_mfma_f32_16x16x32_bf16(a, b, c, 0, 0, 0)
#define PIN(x) asm volatile("" : "+v"(x))

__device__ __forceinline__ US f2bf(float x) {   // RNE fp32 -> bf16 bits
  unsigned int u = __float_as_uint(x);
  unsigned int r = 0x7FFFu + ((u >> 16) & 1u);
  return (US)((u + r) >> 16);
}
__device__ __forceinline__ float bf2f(US u) {
  return __uint_as_float(((unsigned int)u) << 16);
}

__device__ __forceinline__ void gl_lds16(const US* g, US* l) {
  __builtin_amdgcn_global_load_lds((const as1_uint*)g, (as3_uint*)l, 16, 0, 0);
}

// ---- elementwise fp32 -> bf16 hi/lo split ----------------------------------
__global__ __launch_bounds__(256) void split_kernel(
    const float* __restrict__ in, US* __restrict__ hi, US* __restrict__ lo, int n4)
{
  int i = blockIdx.x * 256 + threadIdx.x;
  if (i >= n4) return;
  float4 v = reinterpret_cast<const float4*>(in)[i];
  US h0 = f2bf(v.x), h1 = f2bf(v.y), h2 = f2bf(v.z), h3 = f2bf(v.w);
  ushort4 hv = make_ushort4(h0, h1, h2, h3);
  ushort4 lv = make_ushort4(f2bf(v.x - bf2f(h0)), f2bf(v.y - bf2f(h1)),
                            f2bf(v.z - bf2f(h2)), f2bf(v.w - bf2f(h3)));
  reinterpret_cast<ushort4*>(hi)[i] = hv;
  reinterpret_cast<ushort4*>(lo)[i] = lv;
}

// ---- zero initial h frag buffers + barrier state ---------------------------
__global__ void zero_kernel(US* __restrict__ h0, US* __restrict__ l0,
                            unsigned* __restrict__ bar)
{
  int i = blockIdx.x * 256 + threadIdx.x;   // grid covers 65536 exactly
  h0[i] = 0; l0[i] = 0;
  if (i < 1024) bar[i] = 0;
}

// ---- mproj[j] = sum_k mean[k] * comp[j][k] ---------------------------------
__global__ __launch_bounds__(256) void mproj_kernel(
    const float* __restrict__ mean, const float* __restrict__ comp,
    float* __restrict__ mproj)
{
  int j = blockIdx.x;
  const float* row = comp + (size_t)j * 2048;
  float s = 0.f;
  for (int k = threadIdx.x; k < 2048; k += 256) s += mean[k] * row[k];
  __shared__ float ss[4];
  #pragma unroll
  for (int o = 32; o > 0; o >>= 1) s += __shfl_down(s, o, 64);
  if ((threadIdx.x & 63) == 0) ss[threadIdx.x >> 6] = s;
  __syncthreads();
  if (threadIdx.x == 0) mproj[j] = ss[0] + ss[1] + ss[2] + ss[3];
}

// ---- build KT[j'][k] row-major gate-interleaved transpose (for zx GEMM) ----
// j' = 4*u + g  <->  source col g*2048+u.
__global__ __launch_bounds__(256) void build_kt(
    const float* __restrict__ src, US* __restrict__ t_hi, US* __restrict__ t_lo)
{
  __shared__ float tile[64][65];
  const int jblk = blockIdx.x >> 5;
  const int kblk = blockIdx.x & 31;
  const int j0 = jblk * 64;
  const int u0 = j0 >> 2;
  const int k0 = kblk * 64;
  const int tid = threadIdx.x;
  const int cc = tid & 63;
  const int g = cc >> 4, uo = cc & 15;
  const int col = g * 2048 + u0 + uo;
  const int kl0 = tid >> 6;
  #pragma unroll
  for (int r = 0; r < 16; ++r) {
    int kl = r * 4 + kl0;
    tile[4 * uo + g][kl] = src[(size_t)(k0 + kl) * 8192 + col];
  }
  __syncthreads();
  const int kl = tid & 63;
  const int jl0 = tid >> 6;
  #pragma unroll
  for (int r = 0; r < 16; ++r) {
    int jl = r * 4 + jl0;
    float v = tile[jl][kl];
    US hv = f2bf(v);
    size_t o = (size_t)(j0 + jl) * 2048 + (size_t)(k0 + kl);
    t_hi[o] = hv;
    t_lo[o] = f2bf(v - bf2f(hv));
  }
}

// ---- build fragment-linear split weights W'[j'][k] -------------------------
// lin = ((jg*64+kc)*64+l)*8+e ; jg=j'>>4; kc=k>>5; l=((k>>3)&3)*16+(j'&15); e=k&7
__global__ __launch_bounds__(256) void build_wfrag(
    const float* __restrict__ src, US* __restrict__ t_hi, US* __restrict__ t_lo)
{
  __shared__ float tile[64][68];          // [j'local][k_local]
  const int ub = blockIdx.x >> 5;
  const int kb = blockIdx.x & 31;
  const int u0 = ub * 16, k0 = kb * 64;
  const int jg0 = ub * 4, kc0 = kb * 2;
  const int tid = threadIdx.x;

  const int g = tid >> 6, r2 = (tid >> 2) & 15, c4 = tid & 3;
  #pragma unroll
  for (int rr = 0; rr < 4; ++rr) {
    int row = rr * 16 + r2;
    size_t off = (size_t)(k0 + row) * 8192 + g * 2048 + u0 + c4 * 4;
    float4 v = *reinterpret_cast<const float4*>(src + off);
    tile[4 * (c4 * 4 + 0) + g][row] = v.x;
    tile[4 * (c4 * 4 + 1) + g][row] = v.y;
    tile[4 * (c4 * 4 + 2) + g][row] = v.z;
    tile[4 * (c4 * 4 + 3) + g][row] = v.w;
  }
  __syncthreads();

  #pragma unroll
  for (int it = 0; it < 2; ++it) {
    int idx = it * 256 + tid;
    int l = idx & 63, kcl = (idx >> 6) & 1, jgl = idx >> 7;
    int jloc = jgl * 16 + (l & 15);
    int kl = kcl * 32 + (l >> 4) * 8;
    float4 v0 = *reinterpret_cast<const float4*>(&tile[jloc][kl]);
    float4 v1 = *reinterpret_cast<const float4*>(&tile[jloc][kl + 4]);
    float f[8] = {v0.x, v0.y, v0.z, v0.w, v1.x, v1.y, v1.z, v1.w};
    unsigned int hp[4], lp[4];
    #pragma unroll
    for (int q = 0; q < 4; ++q) {
      US h0 = f2bf(f[2 * q]),     h1 = f2bf(f[2 * q + 1]);
      US s0 = f2bf(f[2 * q] - bf2f(h0));
      US s1 = f2bf(f[2 * q + 1] - bf2f(h1));
      hp[q] = (unsigned int)h0 | ((unsigned int)h1 << 16);
      lp[q] = (unsigned int)s0 | ((unsigned int)s1 << 16);
    }
    size_t base = (((size_t)(jg0 + jgl) * 64 + (kc0 + kcl)) * 64 + l) * 8;
    *reinterpret_cast<uint4*>(t_hi + base) = make_uint4(hp[0], hp[1], hp[2], hp[3]);
    *reinterpret_cast<uint4*>(t_lo + base) = make_uint4(lp[0], lp[1], lp[2], lp[3]);
  }
}

// ---- 128-row tiled GEMM, LDS-staged via global_load_lds, XOR swizzle -------
template<int NT, int EPI>
__global__ __launch_bounds__(256, 2) void gemm128(
    const US* __restrict__ Ah, const US* __restrict__ Al,
    const US* __restrict__ Bh, const US* __restrict__ Bl,
    const float* __restrict__ mproj,
    US* __restrict__ out0, US* __restrict__ out1,
    int MB, int ldo)
{
  constexpr int BN = NT * 32;
  __shared__ US sAh[128 * 64], sAl[128 * 64];
  __shared__ US sBh[BN * 64],  sBl[BN * 64];
  const int tid = threadIdx.x;
  const int w = tid >> 6, l = tid & 63;
  const int l16 = l & 15, lq = l >> 4;
  const int cpx = gridDim.x >> 3;
  const int swz = (blockIdx.x & 7) * cpx + (blockIdx.x >> 3);
  const int bm = swz % MB, bn = swz / MB;
  const int wm = w & 1, wn = w >> 1;
  const int AR0 = bm * 128, BR0 = bn * BN;

  f32x4 acc[4][NT];
  #pragma unroll
  for (int i = 0; i < 4; ++i)
    #pragma unroll
    for (int j = 0; j < NT; ++j) acc[i][j] = {0.f, 0.f, 0.f, 0.f};

  for (int k0 = 0; k0 < 2048; k0 += 64) {
    {
      #pragma unroll
      for (int i = 0; i < 4; ++i) {
        int c = (w * 4 + i) * 64 + l;
        int row = c >> 3, kc = c & 7;
        size_t go = (size_t)(AR0 + row) * 2048 + (k0 + ((kc ^ (row & 7)) << 3));
        gl_lds16(Ah + go, sAh + (w * 4 + i) * 512);
        gl_lds16(Al + go, sAl + (w * 4 + i) * 512);
      }
      constexpr int IPW = BN >> 5;
      #pragma unroll
      for (int i = 0; i < IPW; ++i) {
        int c = (w * IPW + i) * 64 + l;
        int row = c >> 3, kc = c & 7;
        size_t go = (size_t)(BR0 + row) * 2048 + (k0 + ((kc ^ (row & 7)) << 3));
        gl_lds16(Bh + go, sBh + (w * IPW + i) * 512);
        gl_lds16(Bl + go, sBl + (w * IPW + i) * 512);
      }
    }
    __syncthreads();
    #pragma unroll
    for (int ks = 0; ks < 2; ++ks) {
      const int kb = ks * 64 + lq * 16;
      bf16x8 ah[4], al[4], bh[NT], bl[NT];
      #pragma unroll
      for (int mt = 0; mt < 4; ++mt) {
        int r = wm * 64 + mt * 16 + l16;
        int off = r * 64 + ((kb ^ ((r & 7) << 4)) >> 1);
        ah[mt] = *reinterpret_cast<const bf16x8*>(sAh + off);
        al[mt] = *reinterpret_cast<const bf16x8*>(sAl + off);
      }
      #pragma unroll
      for (int nt = 0; nt < NT; ++nt) {
        int r = wn * (BN / 2) + nt * 16 + l16;
        int off = r * 64 + ((kb ^ ((r & 7) << 4)) >> 1);
        bh[nt] = *reinterpret_cast<const bf16x8*>(sBh + off);
        bl[nt] = *reinterpret_cast<const bf16x8*>(sBl + off);
      }
      #pragma unroll
      for (int mt = 0; mt < 4; ++mt)
        #pragma unroll
        for (int nt = 0; nt < NT; ++nt) {
          acc[mt][nt] = MFMA(ah[mt], bh[nt], acc[mt][nt]);
          acc[mt][nt] = MFMA(al[mt], bh[nt], acc[mt][nt]);
          acc[mt][nt] = MFMA(ah[mt], bl[nt], acc[mt][nt]);
        }
    }
    __syncthreads();
  }

  #pragma unroll
  for (int mt = 0; mt < 4; ++mt)
    #pragma unroll
    for (int nt = 0; nt < NT; ++nt) {
      int j = BR0 + wn * (BN / 2) + nt * 16 + l16;
      float mp = (EPI == 0) ? mproj[j] : 0.f;
      #pragma unroll
      for (int r = 0; r < 4; ++r) {
        int m = AR0 + wm * 64 + mt * 16 + lq * 4 + r;
        float v = acc[mt][nt][r] - mp;
        if constexpr (EPI == 0) {
          int t = m & 63, b = m >> 6;
          size_t o = (size_t)(t * 32 + b) * ldo + j;
          US hv = f2bf(v);
          out0[o] = hv;
          out1[o] = f2bf(v - bf2f(hv));
        } else {
          size_t o = (size_t)m * ldo + j;
          US hv = f2bf(v);
          out0[o] = hv;
          out1[o] = f2bf(v - bf2f(hv));
        }
      }
    }
}

// ---- fast device barrier: relaxed spin, single acquire fence ---------------
// 16 leaf counters bar[g*16] (g = b&15, XCD-pure groups of 16), root bar[256],
// generation bar[272]. Cumulative counts; zeroed each launch.
__device__ __forceinline__ void gbar(int s, unsigned* bar)
{
  __syncthreads();                       // all waves' stores issued & drained
  if (threadIdx.x == 0) {
    __builtin_amdgcn_fence(__ATOMIC_RELEASE, "agent");   // publish h/out (wbL2)
    const int g = blockIdx.x & 15;
    unsigned a = __hip_atomic_fetch_add(&bar[g * 16], 1u,
                    __ATOMIC_RELAXED, __HIP_MEMORY_SCOPE_AGENT);
    if (a == (unsigned)(16 * (s + 1) - 1)) {
      unsigned r = __hip_atomic_fetch_add(&bar[256], 1u,
                      __ATOMIC_RELAXED, __HIP_MEMORY_SCOPE_AGENT);
      if (r == (unsigned)(16 * (s + 1) - 1))
        __hip_atomic_store(&bar[272], (unsigned)(s + 1),
                           __ATOMIC_RELAXED, __HIP_MEMORY_SCOPE_AGENT);
    }
    // RELAXED polls: no cache maintenance per iteration
    while (__hip_atomic_load(&bar[272], __ATOMIC_RELAXED,
                             __HIP_MEMORY_SCOPE_AGENT) < (unsigned)(s + 1)) {
      __builtin_amdgcn_s_sleep(4);
    }
    __builtin_amdgcn_fence(__ATOMIC_ACQUIRE, "agent");   // ONE inv at exit
  }
  __syncthreads();
}

// ---- persistent LSTM: all 88 steps, weights resident in VGPRs --------------
// 256 blocks (block b owns units [8b,8b+8) = j' [32b,32b+32)), 512 thr = 8
// waves; wave kq holds W frags for jg in {2b,2b+1}, kc in [8kq,8kq+8).
// amdgpu_waves_per_eu(2,2): 256-VGPR budget so the 128 weight VGPRs stay
// resident (R6 failed because the compiler capped at 128 regs and spilled).
__global__ __launch_bounds__(512)
__attribute__((amdgpu_waves_per_eu(2, 2)))
void lstm_persist(
    const US* __restrict__ rtf_hi, const US* __restrict__ rtf_lo,
    const float* __restrict__ Kmat,
    const US* __restrict__ zx_hi, const US* __restrict__ zx_lo,
    const float* __restrict__ bias,
    US* __restrict__ h_hi0, US* __restrict__ h_lo0,
    US* __restrict__ h_hi1, US* __restrict__ h_lo1,
    unsigned* __restrict__ bar,
    float* __restrict__ out)
{
  __shared__ float red[8][32][33];
  const int tid = threadIdx.x;
  const int kq = tid >> 6, l = tid & 63;
  const int b = blockIdx.x;
  const int l16 = l & 15, lq = l >> 4;

  // ---- load weight fragments (R) into registers and PIN them ----
  bf16x8 Wh[2][8], Wl[2][8];
  #pragma unroll
  for (int jgl = 0; jgl < 2; ++jgl)
    #pragma unroll
    for (int kcl = 0; kcl < 8; ++kcl) {
      size_t o = (((size_t)(b * 2 + jgl) * 64 + kq * 8 + kcl) * 64 + l) * 8;
      Wh[jgl][kcl] = *reinterpret_cast<const bf16x8*>(rtf_hi + o);
      Wl[jgl][kcl] = *reinterpret_cast<const bf16x8*>(rtf_lo + o);
      PIN(Wh[jgl][kcl]);
      PIN(Wl[jgl][kcl]);
    }

  // ---- cell-role constants (tid < 256: one (batch m, unit uu)) ----
  const int m = tid >> 3, uu = tid & 7;
  const int u = b * 8 + uu;
  float bz0 = 0.f, bz1 = 0.f, bz2 = 0.f, bz3 = 0.f, creg = 0.f;
  if (tid < 256) {
    bz0 = bias[u]; bz1 = bias[u + 2048];
    bz2 = bias[u + 4096]; bz3 = bias[u + 6144];
  }
  const int kcw = u >> 5, mhw = m >> 4;
  const int lw = ((u >> 3) & 3) * 16 + (m & 15);
  const size_t hwidx = (((size_t)kcw * 2 + mhw) * 64 + lw) * 8 + (u & 7);

  for (int s = 0; s < 88; ++s) {
    const int par = s & 1;
    const US* hfh = par ? h_hi1 : h_hi0;
    const US* hfl = par ? h_lo1 : h_lo0;
    US* hoh = par ? h_hi0 : h_hi1;
    US* hol = par ? h_lo0 : h_lo1;

    if (s == 64) {
      // transmute W := resplit(R + K); K read fp32 straight from input
      #pragma unroll
      for (int jgl = 0; jgl < 2; ++jgl) {
        const int jp = (b * 2 + jgl) * 16 + l16;       // j' = 4u+g
        const int col = (jp & 3) * 2048 + (jp >> 2);   // source col g*2048+u
        #pragma unroll
        for (int kcl = 0; kcl < 8; ++kcl) {
          const int k0 = (kq * 8 + kcl) * 32 + lq * 8;
          #pragma unroll
          for (int e = 0; e < 8; ++e) {
            float kv = Kmat[(size_t)(k0 + e) * 8192 + col];
            float wv = bf2f((US)Wh[jgl][kcl][e]) + bf2f((US)Wl[jgl][kcl][e]) + kv;
            US hv = f2bf(wv);
            Wh[jgl][kcl][e] = (short)hv;
            Wl[jgl][kcl][e] = (short)f2bf(wv - bf2f(hv));
          }
          PIN(Wh[jgl][kcl]);
          PIN(Wl[jgl][kcl]);
        }
      }
    }

    // ---- partial z: wave kq covers k in [kq*256, kq*256+256) ----
    f32x4 acc00 = {0.f,0.f,0.f,0.f}, acc01 = {0.f,0.f,0.f,0.f};
    f32x4 acc10 = {0.f,0.f,0.f,0.f}, acc11 = {0.f,0.f,0.f,0.f};
    #pragma unroll
    for (int kcl = 0; kcl < 8; ++kcl) {
      const int kc = kq * 8 + kcl;
      const US* ah = hfh + ((size_t)kc * 2 * 64 + l) * 8;
      const US* al = hfl + ((size_t)kc * 2 * 64 + l) * 8;
      bf16x8 a0h = *reinterpret_cast<const bf16x8*>(ah);
      bf16x8 a1h = *reinterpret_cast<const bf16x8*>(ah + 512);
      bf16x8 a0l = *reinterpret_cast<const bf16x8*>(al);
      bf16x8 a1l = *reinterpret_cast<const bf16x8*>(al + 512);
      acc00 = MFMA(a0h, Wh[0][kcl], acc00);
      acc01 = MFMA(a0h, Wh[1][kcl], acc01);
      acc10 = MFMA(a1h, Wh[0][kcl], acc10);
      acc11 = MFMA(a1h, Wh[1][kcl], acc11);
      acc00 = MFMA(a0l, Wh[0][kcl], acc00);
      acc01 = MFMA(a0l, Wh[1][kcl], acc01);
      acc10 = MFMA(a1l, Wh[0][kcl], acc10);
      acc11 = MFMA(a1l, Wh[1][kcl], acc11);
      acc00 = MFMA(a0h, Wl[0][kcl], acc00);
      acc01 = MFMA(a0h, Wl[1][kcl], acc01);
      acc10 = MFMA(a1h, Wl[0][kcl], acc10);
      acc11 = MFMA(a1h, Wl[1][kcl], acc11);
    }

    // ---- write partials, reduce 8-way, cell update ----
    #pragma unroll
    for (int r = 0; r < 4; ++r) {
      red[kq][l16][0 * 16 + lq * 4 + r]       = acc00[r];
      red[kq][16 + l16][0 * 16 + lq * 4 + r]  = acc01[r];
      red[kq][l16][1 * 16 + lq * 4 + r]       = acc10[r];
      red[kq][16 + l16][1 * 16 + lq * 4 + r]  = acc11[r];
    }
    __syncthreads();
    if (tid < 256) {
      float z0 = bz0, z1 = bz1, z2 = bz2, z3 = bz3;
      #pragma unroll
      for (int q = 0; q < 8; ++q) {
        z0 += red[q][uu * 4 + 0][m];
        z1 += red[q][uu * 4 + 1][m];
        z2 += red[q][uu * 4 + 2][m];
        z3 += red[q][uu * 4 + 3][m];
      }
      if (s < 64) {
        size_t zo = (size_t)(s * 32 + m) * 8192 + (size_t)u * 4;
        z0 += bf2f(zx_hi[zo + 0]) + bf2f(zx_lo[zo + 0]);
        z1 += bf2f(zx_hi[zo + 1]) + bf2f(zx_lo[zo + 1]);
        z2 += bf2f(zx_hi[zo + 2]) + bf2f(zx_lo[zo + 2]);
        z3 += bf2f(zx_hi[zo + 3]) + bf2f(zx_lo[zo + 3]);
      }
      float gi = 1.f / (1.f + expf(-z0));
      float gf = 1.f / (1.f + expf(-z1));
      float gg = tanhf(z2);
      float go = 1.f / (1.f + expf(-z3));
      creg = gf * creg + gi * gg;
      float hn = go * tanhf(creg);
      US hv = f2bf(hn);
      hoh[hwidx] = hv;
      hol[hwidx] = f2bf(hn - bf2f(hv));
      if (s >= 64) out[((size_t)m * 24 + (s - 64)) * 2048 + u] = hn;
    }
    gbar(s, bar);
  }
}

// ============================================================================
extern "C" void kernel_launch(void* const* d_in, const int* in_sizes, int n_in,
                              void* d_out, int out_size, void* d_ws, size_t ws_size,
                              hipStream_t stream)
{
  const float* inputs = (const float*)d_in[0];   // (32,64,2048,1)
  const float* comp   = (const float*)d_in[1];   // (2048,2048)
  const float* mean   = (const float*)d_in[2];   // (2048,)
  const float* Kmat   = (const float*)d_in[3];   // (2048,8192)
  const float* Rmat   = (const float*)d_in[4];   // (2048,8192)
  const float* bias   = (const float*)d_in[5];   // (8192,)
  float* out = (float*)d_out;                    // (32,24,2048)

  // ---- workspace layout (177 MiB envelope, proven in R1-R5) ----
  const size_t MiB = 1024 * 1024;
  char* base = (char*)d_ws;
  US* zx_hi   = (US*)(base);                     // [0,32)   2048x8192 bf16
  US* zx_lo   = (US*)(base + 32 * MiB);          // [32,64)
  US* KT_hi   = (US*)(base + 64 * MiB);          // [64,96)  row-major K^T
  US* KT_lo   = (US*)(base + 96 * MiB);          // [96,128)
  US* RTf_hi  = KT_hi;                           // over dead KT (after zx gemm)
  US* RTf_lo  = KT_lo;
  US* flat_hi = (US*)(base + 128 * MiB);         // [128,136)
  US* flat_lo = (US*)(base + 136 * MiB);         // [136,144)
  US* comp_hi = (US*)(base + 144 * MiB);         // [144,152)
  US* comp_lo = (US*)(base + 152 * MiB);         // [152,160)
  US* xs_hi   = (US*)(base + 160 * MiB);         // [160,168)
  US* xs_lo   = (US*)(base + 168 * MiB);         // [168,176)
  char* Mz = base + 176 * MiB;
  float* mproj = (float*)(Mz);
  US* hh0 = (US*)(Mz + 64 * 1024);
  US* hl0 = (US*)(Mz + 256 * 1024);
  US* hh1 = (US*)(Mz + 448 * 1024);
  US* hl1 = (US*)(Mz + 640 * 1024);
  unsigned* bar = (unsigned*)(Mz + 832 * 1024);  // 4 KiB barrier state

  // ---- prep ----
  split_kernel<<<4096, 256, 0, stream>>>(inputs, flat_hi, flat_lo, 1048576);
  split_kernel<<<4096, 256, 0, stream>>>(comp,   comp_hi, comp_lo, 1048576);
  mproj_kernel<<<2048, 256, 0, stream>>>(mean, comp, mproj);
  build_kt<<<4096, 256, 0, stream>>>(Kmat, KT_hi, KT_lo);
  zero_kernel<<<256, 256, 0, stream>>>(hh0, hl0, bar);

  // xs = (flat - mean) @ comp^T  (2048 x 2048), rows remapped to t*32+b
  gemm128<2, 0><<<512, 256, 0, stream>>>(flat_hi, flat_lo, comp_hi, comp_lo,
                                         mproj, xs_hi, xs_lo, 16, 2048);
  // zx = xs @ K^T  (2048 x 8192, gate-interleaved cols), bf16 hi/lo store
  gemm128<4, 2><<<1024, 256, 0, stream>>>(xs_hi, xs_lo, KT_hi, KT_lo,
                                          nullptr, zx_hi, zx_lo, 16, 8192);
  // RTf (fragment-linear R^T) over the now-dead KT region
  build_wfrag<<<4096, 256, 0, stream>>>(Rmat, RTf_hi, RTf_lo);

  // ---- all 88 steps in one persistent kernel (cooperative launch for
  //      guaranteed co-residency; custom barrier used inside) ----
  const US* a_rtf_hi = RTf_hi; const US* a_rtf_lo = RTf_lo;
  const float* a_kmat = Kmat;
  const US* a_zx_hi = zx_hi;   const US* a_zx_lo = zx_lo;
  const float* a_bias = bias;
  US* a_hh0 = hh0; US* a_hl0 = hl0; US* a_hh1 = hh1; US* a_hl1 = hl1;
  unsigned* a_bar = bar;
  float* a_out = out;
  void* args[] = {
    (void*)&a_rtf_hi, (void*)&a_rtf_lo, (void*)&a_kmat,
    (void*)&a_zx_hi, (void*)&a_zx_lo, (void*)&a_bias,
    (void*)&a_hh0, (void*)&a_hl0, (void*)&a_hh1, (void*)&a_hl1,
    (void*)&a_bar, (void*)&a_out
  };
  hipLaunchCooperativeKernel((void*)lstm_persist, dim3(256), dim3(512),
                             args, 0, stream);
}

// Round 8
// 1853.373 us; speedup vs baseline: 4.3301x; 1.0034x over previous
//
#include <hip/hip_runtime.h>
#include <math.h>

// ============================================================================
// PCA + LSTM encoder/decoder on MI355X.
//  - GEMMs: mfma_f32_16x16x32_bf16, 3-term split-bf16 (hi/lo) ~ fp32 accuracy.
//  - Encoder x@K precomputed for all 64 steps in ONE GEMM (zx, bf16 hi/lo).
//  - All 88 recurrent steps in ONE persistent cooperative-launched kernel.
//    * Weights in VGPRs. KEY FIX vs R7: PIN(W) executes INSIDE the step loop
//      (once per step). R7 pinned only at load time, so the compiler legally
//      "rematerialized" the weights by re-loading them from memory every step
//      (VGPR_Count stayed 128, 64 MB/step re-streamed, 18 us/step). An asm
//      "+v" in the loop body makes reload illegal -> true residency.
//    * waves_per_eu(2,2): 256-VGPR budget (128 weights + ~80 working fits).
//    * Custom barrier: RELAXED spin + ONE acquire fence at exit (R6 fix).
//  - At step 64 weights transmute in-place to K+R (Kmat read fp32, once).
//  - Workspace: 177 MiB envelope proven in R1-R7 + 4 KiB barrier state.
// ============================================================================

typedef unsigned short US;
typedef __attribute__((ext_vector_type(8))) short bf16x8;
typedef __attribute__((ext_vector_type(4))) float f32x4;

typedef __attribute__((address_space(3))) unsigned int as3_uint;
typedef __attribute__((address_space(1))) unsigned int as1_uint;

#define MFMA(a, b, c) __builtin_amdgcn_mfma_f32_16x16x32_bf16(a, b, c, 0, 0, 0)
#define PIN(x) asm volatile("" : "+v"(x))

__device__ __forceinline__ US f2bf(float x) {   // RNE fp32 -> bf16 bits
  unsigned int u = __float_as_uint(x);
  unsigned int r = 0x7FFFu + ((u >> 16) & 1u);
  return (US)((u + r) >> 16);
}
__device__ __forceinline__ float bf2f(US u) {
  return __uint_as_float(((unsigned int)u) << 16);
}

__device__ __forceinline__ void gl_lds16(const US* g, US* l) {
  __builtin_amdgcn_global_load_lds((const as1_uint*)g, (as3_uint*)l, 16, 0, 0);
}

// ---- elementwise fp32 -> bf16 hi/lo split ----------------------------------
__global__ __launch_bounds__(256) void split_kernel(
    const float* __restrict__ in, US* __restrict__ hi, US* __restrict__ lo, int n4)
{
  int i = blockIdx.x * 256 + threadIdx.x;
  if (i >= n4) return;
  float4 v = reinterpret_cast<const float4*>(in)[i];
  US h0 = f2bf(v.x), h1 = f2bf(v.y), h2 = f2bf(v.z), h3 = f2bf(v.w);
  ushort4 hv = make_ushort4(h0, h1, h2, h3);
  ushort4 lv = make_ushort4(f2bf(v.x - bf2f(h0)), f2bf(v.y - bf2f(h1)),
                            f2bf(v.z - bf2f(h2)), f2bf(v.w - bf2f(h3)));
  reinterpret_cast<ushort4*>(hi)[i] = hv;
  reinterpret_cast<ushort4*>(lo)[i] = lv;
}

// ---- zero initial h frag buffers + barrier state ---------------------------
__global__ void zero_kernel(US* __restrict__ h0, US* __restrict__ l0,
                            unsigned* __restrict__ bar)
{
  int i = blockIdx.x * 256 + threadIdx.x;   // grid covers 65536 exactly
  h0[i] = 0; l0[i] = 0;
  if (i < 1024) bar[i] = 0;
}

// ---- mproj[j] = sum_k mean[k] * comp[j][k] ---------------------------------
__global__ __launch_bounds__(256) void mproj_kernel(
    const float* __restrict__ mean, const float* __restrict__ comp,
    float* __restrict__ mproj)
{
  int j = blockIdx.x;
  const float* row = comp + (size_t)j * 2048;
  float s = 0.f;
  for (int k = threadIdx.x; k < 2048; k += 256) s += mean[k] * row[k];
  __shared__ float ss[4];
  #pragma unroll
  for (int o = 32; o > 0; o >>= 1) s += __shfl_down(s, o, 64);
  if ((threadIdx.x & 63) == 0) ss[threadIdx.x >> 6] = s;
  __syncthreads();
  if (threadIdx.x == 0) mproj[j] = ss[0] + ss[1] + ss[2] + ss[3];
}

// ---- build KT[j'][k] row-major gate-interleaved transpose (for zx GEMM) ----
// j' = 4*u + g  <->  source col g*2048+u.
__global__ __launch_bounds__(256) void build_kt(
    const float* __restrict__ src, US* __restrict__ t_hi, US* __restrict__ t_lo)
{
  __shared__ float tile[64][65];
  const int jblk = blockIdx.x >> 5;
  const int kblk = blockIdx.x & 31;
  const int j0 = jblk * 64;
  const int u0 = j0 >> 2;
  const int k0 = kblk * 64;
  const int tid = threadIdx.x;
  const int cc = tid & 63;
  const int g = cc >> 4, uo = cc & 15;
  const int col = g * 2048 + u0 + uo;
  const int kl0 = tid >> 6;
  #pragma unroll
  for (int r = 0; r < 16; ++r) {
    int kl = r * 4 + kl0;
    tile[4 * uo + g][kl] = src[(size_t)(k0 + kl) * 8192 + col];
  }
  __syncthreads();
  const int kl = tid & 63;
  const int jl0 = tid >> 6;
  #pragma unroll
  for (int r = 0; r < 16; ++r) {
    int jl = r * 4 + jl0;
    float v = tile[jl][kl];
    US hv = f2bf(v);
    size_t o = (size_t)(j0 + jl) * 2048 + (size_t)(k0 + kl);
    t_hi[o] = hv;
    t_lo[o] = f2bf(v - bf2f(hv));
  }
}

// ---- build fragment-linear split weights W'[j'][k] -------------------------
// lin = ((jg*64+kc)*64+l)*8+e ; jg=j'>>4; kc=k>>5; l=((k>>3)&3)*16+(j'&15); e=k&7
__global__ __launch_bounds__(256) void build_wfrag(
    const float* __restrict__ src, US* __restrict__ t_hi, US* __restrict__ t_lo)
{
  __shared__ float tile[64][68];          // [j'local][k_local]
  const int ub = blockIdx.x >> 5;
  const int kb = blockIdx.x & 31;
  const int u0 = ub * 16, k0 = kb * 64;
  const int jg0 = ub * 4, kc0 = kb * 2;
  const int tid = threadIdx.x;

  const int g = tid >> 6, r2 = (tid >> 2) & 15, c4 = tid & 3;
  #pragma unroll
  for (int rr = 0; rr < 4; ++rr) {
    int row = rr * 16 + r2;
    size_t off = (size_t)(k0 + row) * 8192 + g * 2048 + u0 + c4 * 4;
    float4 v = *reinterpret_cast<const float4*>(src + off);
    tile[4 * (c4 * 4 + 0) + g][row] = v.x;
    tile[4 * (c4 * 4 + 1) + g][row] = v.y;
    tile[4 * (c4 * 4 + 2) + g][row] = v.z;
    tile[4 * (c4 * 4 + 3) + g][row] = v.w;
  }
  __syncthreads();

  #pragma unroll
  for (int it = 0; it < 2; ++it) {
    int idx = it * 256 + tid;
    int l = idx & 63, kcl = (idx >> 6) & 1, jgl = idx >> 7;
    int jloc = jgl * 16 + (l & 15);
    int kl = kcl * 32 + (l >> 4) * 8;
    float4 v0 = *reinterpret_cast<const float4*>(&tile[jloc][kl]);
    float4 v1 = *reinterpret_cast<const float4*>(&tile[jloc][kl + 4]);
    float f[8] = {v0.x, v0.y, v0.z, v0.w, v1.x, v1.y, v1.z, v1.w};
    unsigned int hp[4], lp[4];
    #pragma unroll
    for (int q = 0; q < 4; ++q) {
      US h0 = f2bf(f[2 * q]),     h1 = f2bf(f[2 * q + 1]);
      US s0 = f2bf(f[2 * q] - bf2f(h0));
      US s1 = f2bf(f[2 * q + 1] - bf2f(h1));
      hp[q] = (unsigned int)h0 | ((unsigned int)h1 << 16);
      lp[q] = (unsigned int)s0 | ((unsigned int)s1 << 16);
    }
    size_t base = (((size_t)(jg0 + jgl) * 64 + (kc0 + kcl)) * 64 + l) * 8;
    *reinterpret_cast<uint4*>(t_hi + base) = make_uint4(hp[0], hp[1], hp[2], hp[3]);
    *reinterpret_cast<uint4*>(t_lo + base) = make_uint4(lp[0], lp[1], lp[2], lp[3]);
  }
}

// ---- 128-row tiled GEMM, LDS-staged via global_load_lds, XOR swizzle -------
template<int NT, int EPI>
__global__ __launch_bounds__(256, 2) void gemm128(
    const US* __restrict__ Ah, const US* __restrict__ Al,
    const US* __restrict__ Bh, const US* __restrict__ Bl,
    const float* __restrict__ mproj,
    US* __restrict__ out0, US* __restrict__ out1,
    int MB, int ldo)
{
  constexpr int BN = NT * 32;
  __shared__ US sAh[128 * 64], sAl[128 * 64];
  __shared__ US sBh[BN * 64],  sBl[BN * 64];
  const int tid = threadIdx.x;
  const int w = tid >> 6, l = tid & 63;
  const int l16 = l & 15, lq = l >> 4;
  const int cpx = gridDim.x >> 3;
  const int swz = (blockIdx.x & 7) * cpx + (blockIdx.x >> 3);
  const int bm = swz % MB, bn = swz / MB;
  const int wm = w & 1, wn = w >> 1;
  const int AR0 = bm * 128, BR0 = bn * BN;

  f32x4 acc[4][NT];
  #pragma unroll
  for (int i = 0; i < 4; ++i)
    #pragma unroll
    for (int j = 0; j < NT; ++j) acc[i][j] = {0.f, 0.f, 0.f, 0.f};

  for (int k0 = 0; k0 < 2048; k0 += 64) {
    {
      #pragma unroll
      for (int i = 0; i < 4; ++i) {
        int c = (w * 4 + i) * 64 + l;
        int row = c >> 3, kc = c & 7;
        size_t go = (size_t)(AR0 + row) * 2048 + (k0 + ((kc ^ (row & 7)) << 3));
        gl_lds16(Ah + go, sAh + (w * 4 + i) * 512);
        gl_lds16(Al + go, sAl + (w * 4 + i) * 512);
      }
      constexpr int IPW = BN >> 5;
      #pragma unroll
      for (int i = 0; i < IPW; ++i) {
        int c = (w * IPW + i) * 64 + l;
        int row = c >> 3, kc = c & 7;
        size_t go = (size_t)(BR0 + row) * 2048 + (k0 + ((kc ^ (row & 7)) << 3));
        gl_lds16(Bh + go, sBh + (w * IPW + i) * 512);
        gl_lds16(Bl + go, sBl + (w * IPW + i) * 512);
      }
    }
    __syncthreads();
    #pragma unroll
    for (int ks = 0; ks < 2; ++ks) {
      const int kb = ks * 64 + lq * 16;
      bf16x8 ah[4], al[4], bh[NT], bl[NT];
      #pragma unroll
      for (int mt = 0; mt < 4; ++mt) {
        int r = wm * 64 + mt * 16 + l16;
        int off = r * 64 + ((kb ^ ((r & 7) << 4)) >> 1);
        ah[mt] = *reinterpret_cast<const bf16x8*>(sAh + off);
        al[mt] = *reinterpret_cast<const bf16x8*>(sAl + off);
      }
      #pragma unroll
      for (int nt = 0; nt < NT; ++nt) {
        int r = wn * (BN / 2) + nt * 16 + l16;
        int off = r * 64 + ((kb ^ ((r & 7) << 4)) >> 1);
        bh[nt] = *reinterpret_cast<const bf16x8*>(sBh + off);
        bl[nt] = *reinterpret_cast<const bf16x8*>(sBl + off);
      }
      #pragma unroll
      for (int mt = 0; mt < 4; ++mt)
        #pragma unroll
        for (int nt = 0; nt < NT; ++nt) {
          acc[mt][nt] = MFMA(ah[mt], bh[nt], acc[mt][nt]);
          acc[mt][nt] = MFMA(al[mt], bh[nt], acc[mt][nt]);
          acc[mt][nt] = MFMA(ah[mt], bl[nt], acc[mt][nt]);
        }
    }
    __syncthreads();
  }

  #pragma unroll
  for (int mt = 0; mt < 4; ++mt)
    #pragma unroll
    for (int nt = 0; nt < NT; ++nt) {
      int j = BR0 + wn * (BN / 2) + nt * 16 + l16;
      float mp = (EPI == 0) ? mproj[j] : 0.f;
      #pragma unroll
      for (int r = 0; r < 4; ++r) {
        int m = AR0 + wm * 64 + mt * 16 + lq * 4 + r;
        float v = acc[mt][nt][r] - mp;
        if constexpr (EPI == 0) {
          int t = m & 63, b = m >> 6;
          size_t o = (size_t)(t * 32 + b) * ldo + j;
          US hv = f2bf(v);
          out0[o] = hv;
          out1[o] = f2bf(v - bf2f(hv));
        } else {
          size_t o = (size_t)m * ldo + j;
          US hv = f2bf(v);
          out0[o] = hv;
          out1[o] = f2bf(v - bf2f(hv));
        }
      }
    }
}

// ---- fast device barrier: relaxed spin, single acquire fence ---------------
// 16 leaf counters bar[g*16] (g = b&15), root bar[256], generation bar[272].
// Cumulative counts; zeroed each launch.
__device__ __forceinline__ void gbar(int s, unsigned* bar)
{
  __syncthreads();                       // all waves' stores issued & drained
  if (threadIdx.x == 0) {
    __builtin_amdgcn_fence(__ATOMIC_RELEASE, "agent");   // publish h/out (wbL2)
    const int g = blockIdx.x & 15;
    unsigned a = __hip_atomic_fetch_add(&bar[g * 16], 1u,
                    __ATOMIC_RELAXED, __HIP_MEMORY_SCOPE_AGENT);
    if (a == (unsigned)(16 * (s + 1) - 1)) {
      unsigned r = __hip_atomic_fetch_add(&bar[256], 1u,
                      __ATOMIC_RELAXED, __HIP_MEMORY_SCOPE_AGENT);
      if (r == (unsigned)(16 * (s + 1) - 1))
        __hip_atomic_store(&bar[272], (unsigned)(s + 1),
                           __ATOMIC_RELAXED, __HIP_MEMORY_SCOPE_AGENT);
    }
    // RELAXED polls: no cache maintenance per iteration
    while (__hip_atomic_load(&bar[272], __ATOMIC_RELAXED,
                             __HIP_MEMORY_SCOPE_AGENT) < (unsigned)(s + 1)) {
      __builtin_amdgcn_s_sleep(4);
    }
    __builtin_amdgcn_fence(__ATOMIC_ACQUIRE, "agent");   // ONE inv at exit
  }
  __syncthreads();
}

// ---- persistent LSTM: all 88 steps, weights resident in VGPRs --------------
// 256 blocks (block b owns units [8b,8b+8) = j' [32b,32b+32)), 512 thr = 8
// waves; wave kq holds W frags for jg in {2b,2b+1}, kc in [8kq,8kq+8).
__global__ __launch_bounds__(512)
__attribute__((amdgpu_waves_per_eu(2, 2)))
void lstm_persist(
    const US* __restrict__ rtf_hi, const US* __restrict__ rtf_lo,
    const float* __restrict__ Kmat,
    const US* __restrict__ zx_hi, const US* __restrict__ zx_lo,
    const float* __restrict__ bias,
    US* __restrict__ h_hi0, US* __restrict__ h_lo0,
    US* __restrict__ h_hi1, US* __restrict__ h_lo1,
    unsigned* __restrict__ bar,
    float* __restrict__ out)
{
  __shared__ float red[8][32][33];
  const int tid = threadIdx.x;
  const int kq = tid >> 6, l = tid & 63;
  const int b = blockIdx.x;
  const int l16 = l & 15, lq = l >> 4;

  // ---- load weight fragments (R) into registers ----
  bf16x8 Wh[2][8], Wl[2][8];
  #pragma unroll
  for (int jgl = 0; jgl < 2; ++jgl)
    #pragma unroll
    for (int kcl = 0; kcl < 8; ++kcl) {
      size_t o = (((size_t)(b * 2 + jgl) * 64 + kq * 8 + kcl) * 64 + l) * 8;
      Wh[jgl][kcl] = *reinterpret_cast<const bf16x8*>(rtf_hi + o);
      Wl[jgl][kcl] = *reinterpret_cast<const bf16x8*>(rtf_lo + o);
    }

  // ---- cell-role constants (tid < 256: one (batch m, unit uu)) ----
  const int m = tid >> 3, uu = tid & 7;
  const int u = b * 8 + uu;
  float bz0 = 0.f, bz1 = 0.f, bz2 = 0.f, bz3 = 0.f, creg = 0.f;
  if (tid < 256) {
    bz0 = bias[u]; bz1 = bias[u + 2048];
    bz2 = bias[u + 4096]; bz3 = bias[u + 6144];
  }
  const int kcw = u >> 5, mhw = m >> 4;
  const int lw = ((u >> 3) & 3) * 16 + (m & 15);
  const size_t hwidx = (((size_t)kcw * 2 + mhw) * 64 + lw) * 8 + (u & 7);

  for (int s = 0; s < 88; ++s) {
    const int par = s & 1;
    const US* hfh = par ? h_hi1 : h_hi0;
    const US* hfl = par ? h_lo1 : h_lo0;
    US* hoh = par ? h_hi0 : h_hi1;
    US* hol = par ? h_lo0 : h_lo1;

    if (s == 64) {
      // transmute W := resplit(R + K); K read fp32 straight from input
      #pragma unroll
      for (int jgl = 0; jgl < 2; ++jgl) {
        const int jp = (b * 2 + jgl) * 16 + l16;       // j' = 4u+g
        const int col = (jp & 3) * 2048 + (jp >> 2);   // source col g*2048+u
        #pragma unroll
        for (int kcl = 0; kcl < 8; ++kcl) {
          const int k0 = (kq * 8 + kcl) * 32 + lq * 8;
          #pragma unroll
          for (int e = 0; e < 8; ++e) {
            float kv = Kmat[(size_t)(k0 + e) * 8192 + col];
            float wv = bf2f((US)Wh[jgl][kcl][e]) + bf2f((US)Wl[jgl][kcl][e]) + kv;
            US hv = f2bf(wv);
            Wh[jgl][kcl][e] = (short)hv;
            Wl[jgl][kcl][e] = (short)f2bf(wv - bf2f(hv));
          }
        }
      }
    }

    // ---- KEY FIX: pin weight registers EVERY step. The asm "+v" marks them
    // as potentially modified, so the compiler cannot rematerialize them by
    // re-loading from rtf_* (which is what R7 did every step). ----
    #pragma unroll
    for (int jgl = 0; jgl < 2; ++jgl)
      #pragma unroll
      for (int kcl = 0; kcl < 8; ++kcl) {
        PIN(Wh[jgl][kcl]);
        PIN(Wl[jgl][kcl]);
      }

    // ---- partial z: wave kq covers k in [kq*256, kq*256+256) ----
    f32x4 acc00 = {0.f,0.f,0.f,0.f}, acc01 = {0.f,0.f,0.f,0.f};
    f32x4 acc10 = {0.f,0.f,0.f,0.f}, acc11 = {0.f,0.f,0.f,0.f};
    #pragma unroll
    for (int kcl = 0; kcl < 8; ++kcl) {
      const int kc = kq * 8 + kcl;
      const US* ah = hfh + ((size_t)kc * 2 * 64 + l) * 8;
      const US* al = hfl + ((size_t)kc * 2 * 64 + l) * 8;
      bf16x8 a0h = *reinterpret_cast<const bf16x8*>(ah);
      bf16x8 a1h = *reinterpret_cast<const bf16x8*>(ah + 512);
      bf16x8 a0l = *reinterpret_cast<const bf16x8*>(al);
      bf16x8 a1l = *reinterpret_cast<const bf16x8*>(al + 512);
      acc00 = MFMA(a0h, Wh[0][kcl], acc00);
      acc01 = MFMA(a0h, Wh[1][kcl], acc01);
      acc10 = MFMA(a1h, Wh[0][kcl], acc10);
      acc11 = MFMA(a1h, Wh[1][kcl], acc11);
      acc00 = MFMA(a0l, Wh[0][kcl], acc00);
      acc01 = MFMA(a0l, Wh[1][kcl], acc01);
      acc10 = MFMA(a1l, Wh[0][kcl], acc10);
      acc11 = MFMA(a1l, Wh[1][kcl], acc11);
      acc00 = MFMA(a0h, Wl[0][kcl], acc00);
      acc01 = MFMA(a0h, Wl[1][kcl], acc01);
      acc10 = MFMA(a1h, Wl[0][kcl], acc10);
      acc11 = MFMA(a1h, Wl[1][kcl], acc11);
    }

    // ---- write partials, reduce 8-way, cell update ----
    #pragma unroll
    for (int r = 0; r < 4; ++r) {
      red[kq][l16][0 * 16 + lq * 4 + r]       = acc00[r];
      red[kq][16 + l16][0 * 16 + lq * 4 + r]  = acc01[r];
      red[kq][l16][1 * 16 + lq * 4 + r]       = acc10[r];
      red[kq][16 + l16][1 * 16 + lq * 4 + r]  = acc11[r];
    }
    __syncthreads();
    if (tid < 256) {
      float z0 = bz0, z1 = bz1, z2 = bz2, z3 = bz3;
      #pragma unroll
      for (int q = 0; q < 8; ++q) {
        z0 += red[q][uu * 4 + 0][m];
        z1 += red[q][uu * 4 + 1][m];
        z2 += red[q][uu * 4 + 2][m];
        z3 += red[q][uu * 4 + 3][m];
      }
      if (s < 64) {
        size_t zo = (size_t)(s * 32 + m) * 8192 + (size_t)u * 4;
        z0 += bf2f(zx_hi[zo + 0]) + bf2f(zx_lo[zo + 0]);
        z1 += bf2f(zx_hi[zo + 1]) + bf2f(zx_lo[zo + 1]);
        z2 += bf2f(zx_hi[zo + 2]) + bf2f(zx_lo[zo + 2]);
        z3 += bf2f(zx_hi[zo + 3]) + bf2f(zx_lo[zo + 3]);
      }
      float gi = 1.f / (1.f + expf(-z0));
      float gf = 1.f / (1.f + expf(-z1));
      float gg = tanhf(z2);
      float go = 1.f / (1.f + expf(-z3));
      creg = gf * creg + gi * gg;
      float hn = go * tanhf(creg);
      US hv = f2bf(hn);
      hoh[hwidx] = hv;
      hol[hwidx] = f2bf(hn - bf2f(hv));
      if (s >= 64) out[((size_t)m * 24 + (s - 64)) * 2048 + u] = hn;
    }
    gbar(s, bar);
  }
}

// ============================================================================
extern "C" void kernel_launch(void* const* d_in, const int* in_sizes, int n_in,
                              void* d_out, int out_size, void* d_ws, size_t ws_size,
                              hipStream_t stream)
{
  const float* inputs = (const float*)d_in[0];   // (32,64,2048,1)
  const float* comp   = (const float*)d_in[1];   // (2048,2048)
  const float* mean   = (const float*)d_in[2];   // (2048,)
  const float* Kmat   = (const float*)d_in[3];   // (2048,8192)
  const float* Rmat   = (const float*)d_in[4];   // (2048,8192)
  const float* bias   = (const float*)d_in[5];   // (8192,)
  float* out = (float*)d_out;                    // (32,24,2048)

  // ---- workspace layout (177 MiB envelope, proven in R1-R7) ----
  const size_t MiB = 1024 * 1024;
  char* base = (char*)d_ws;
  US* zx_hi   = (US*)(base);                     // [0,32)   2048x8192 bf16
  US* zx_lo   = (US*)(base + 32 * MiB);          // [32,64)
  US* KT_hi   = (US*)(base + 64 * MiB);          // [64,96)  row-major K^T
  US* KT_lo   = (US*)(base + 96 * MiB);          // [96,128)
  US* RTf_hi  = KT_hi;                           // over dead KT (after zx gemm)
  US* RTf_lo  = KT_lo;
  US* flat_hi = (US*)(base + 128 * MiB);         // [128,136)
  US* flat_lo = (US*)(base + 136 * MiB);         // [136,144)
  US* comp_hi = (US*)(base + 144 * MiB);         // [144,152)
  US* comp_lo = (US*)(base + 152 * MiB);         // [152,160)
  US* xs_hi   = (US*)(base + 160 * MiB);         // [160,168)
  US* xs_lo   = (US*)(base + 168 * MiB);         // [168,176)
  char* Mz = base + 176 * MiB;
  float* mproj = (float*)(Mz);
  US* hh0 = (US*)(Mz + 64 * 1024);
  US* hl0 = (US*)(Mz + 256 * 1024);
  US* hh1 = (US*)(Mz + 448 * 1024);
  US* hl1 = (US*)(Mz + 640 * 1024);
  unsigned* bar = (unsigned*)(Mz + 832 * 1024);  // 4 KiB barrier state

  // ---- prep ----
  split_kernel<<<4096, 256, 0, stream>>>(inputs, flat_hi, flat_lo, 1048576);
  split_kernel<<<4096, 256, 0, stream>>>(comp,   comp_hi, comp_lo, 1048576);
  mproj_kernel<<<2048, 256, 0, stream>>>(mean, comp, mproj);
  build_kt<<<4096, 256, 0, stream>>>(Kmat, KT_hi, KT_lo);
  zero_kernel<<<256, 256, 0, stream>>>(hh0, hl0, bar);

  // xs = (flat - mean) @ comp^T  (2048 x 2048), rows remapped to t*32+b
  gemm128<2, 0><<<512, 256, 0, stream>>>(flat_hi, flat_lo, comp_hi, comp_lo,
                                         mproj, xs_hi, xs_lo, 16, 2048);
  // zx = xs @ K^T  (2048 x 8192, gate-interleaved cols), bf16 hi/lo store
  gemm128<4, 2><<<1024, 256, 0, stream>>>(xs_hi, xs_lo, KT_hi, KT_lo,
                                          nullptr, zx_hi, zx_lo, 16, 8192);
  // RTf (fragment-linear R^T) over the now-dead KT region
  build_wfrag<<<4096, 256, 0, stream>>>(Rmat, RTf_hi, RTf_lo);

  // ---- all 88 steps in one persistent kernel (cooperative launch for
  //      guaranteed co-residency; custom barrier used inside) ----
  const US* a_rtf_hi = RTf_hi; const US* a_rtf_lo = RTf_lo;
  const float* a_kmat = Kmat;
  const US* a_zx_hi = zx_hi;   const US* a_zx_lo = zx_lo;
  const float* a_bias = bias;
  US* a_hh0 = hh0; US* a_hl0 = hl0; US* a_hh1 = hh1; US* a_hl1 = hl1;
  unsigned* a_bar = bar;
  float* a_out = out;
  void* args[] = {
    (void*)&a_rtf_hi, (void*)&a_rtf_lo, (void*)&a_kmat,
    (void*)&a_zx_hi, (void*)&a_zx_lo, (void*)&a_bias,
    (void*)&a_hh0, (void*)&a_hl0, (void*)&a_hh1, (void*)&a_hl1,
    (void*)&a_bar, (void*)&a_out
  };
  hipLaunchCooperativeKernel((void*)lstm_persist, dim3(256), dim3(512),
                             args, 0, stream);
}